// Round 2
// baseline (615.814 us; speedup 1.0000x reference)
//
#include <hip/hip_runtime.h>
#include <hip/hip_bf16.h>

#define NVOX 200000
#define CCH  128
#define KTOT 384
#define EPS_BN 1e-5f

typedef __bf16 bf16x8 __attribute__((ext_vector_type(8)));
typedef float  floatx4 __attribute__((ext_vector_type(4)));

// ---- workspace layout (bytes) ----
#define XBF_OFF    0ull
#define XBF_BYTES  ((size_t)(NVOX + 1) * CCH * 2)      // bf16 features + zero row
#define WT_OFF     (XBF_OFF + XBF_BYTES)
#define WT_BYTES   ((size_t)3 * CCH * KTOT * 2)        // WT[a][c][k] bf16
#define OUTB_OFF   (WT_OFF + WT_BYTES)
#define OUTB_BYTES ((size_t)3 * NVOX * CCH * 2)        // pre-BN out, bf16
#define STATS_OFF  (OUTB_OFF + OUTB_BYTES)
#define STATS_BYTES ((size_t)3 * 2 * CCH * 4)          // sum/sumsq fp32
#define SC_OFF     (STATS_OFF + STATS_BYTES)           // scale[384], shift[384] fp32

// Cast features -> bf16, append one zero row at index NVOX (sentinel gathers read zeros).
__global__ void k_prep_x(const float* __restrict__ xf, __bf16* __restrict__ xbf) {
    int idx = blockIdx.x * blockDim.x + threadIdx.x;   // one 8-channel chunk
    const int total = (NVOX + 1) * 16;
    if (idx >= total) return;
    float v[8];
    if (idx < NVOX * 16) {
        const float4* p = (const float4*)xf + (size_t)idx * 2;
        float4 f0 = p[0], f1 = p[1];
        v[0] = f0.x; v[1] = f0.y; v[2] = f0.z; v[3] = f0.w;
        v[4] = f1.x; v[5] = f1.y; v[6] = f1.z; v[7] = f1.w;
    } else {
        #pragma unroll
        for (int j = 0; j < 8; ++j) v[j] = 0.0f;
    }
    bf16x8 o;
    #pragma unroll
    for (int j = 0; j < 8; ++j) o[j] = (__bf16)v[j];
    *((bf16x8*)xbf + idx) = o;
}

// W[3][3][C][C] (k,c) -> WT[3][C][KTOT] bf16 where k = s*128 + k0 (prev|self|next concat).
__global__ void k_prep_w(const float* __restrict__ W, __bf16* __restrict__ wt) {
    int idx = blockIdx.x * blockDim.x + threadIdx.x;
    if (idx >= 3 * CCH * KTOT) return;
    int k = idx % KTOT; int rem = idx / KTOT;
    int c = rem % CCH;  int a = rem / CCH;
    int s = k >> 7, k0 = k & 127;
    wt[idx] = (__bf16)W[(((size_t)(a * 3 + s) * CCH) + k0) * CCH + c];
}

// One block = one 64-row M-tile of one axis. 4 waves in 2x2 (rows x cols):
// wave w -> rows [ (w&1)*32, +32 ), cols [ (w>>1)*64, +64 ).
// A tile (64 x 384 bf16) staged via global_load_lds DMA into chunk-contiguous LDS
// (48 x 16B chunks per row, XOR-swizzled by (r&7) to kill ds_read_b128 bank conflicts).
// B double-buffered in registers (distance-1 prefetch from L2-resident WT).
__launch_bounds__(256, 3)
__global__ void k_gemm(const __bf16* __restrict__ xbf, const __bf16* __restrict__ wt,
                       const int* __restrict__ nb, __bf16* __restrict__ outb,
                       float* __restrict__ stats) {
    __shared__ __bf16 smem[64 * 48 * 8];   // 49152 B: A tile, then reused for out tile
    __shared__ int s_pn[128];              // [0..63] prev idx, [64..127] next idx

    const int a    = blockIdx.y;
    const int row0 = blockIdx.x * 64;
    const int tid  = threadIdx.x;
    const int w    = tid >> 6;
    const int lane = tid & 63;
    const int q    = lane >> 4;
    const int ln   = lane & 15;
    const int wm   = w & 1;     // row half
    const int wn   = w >> 1;    // col half

    if (tid < 128) {
        int s = tid >> 6;       // 0: prev, 1: next
        int r = tid & 63;
        s_pn[tid] = nb[(size_t)(a * 2 + s) * NVOX + row0 + r];
    }
    __syncthreads();   // s_pn ready

    // ---- async stage A tile: 3072 chunks of 16B, DMA direct to LDS ----
    // chunk cc holds data D[r][seg] with r=cc/48, seg=(cc%48)^(r&7);
    // seg: 0-15 prev, 16-31 self, 32-47 next; 8 channels per chunk.
    #pragma unroll
    for (int it = 0; it < 12; ++it) {
        int cc = it * 256 + tid;
        int r  = cc / 48;
        int s0 = cc - r * 48;
        int se = s0 ^ (r & 7);
        int src = se >> 4, ch = se & 15;
        int g = (src == 1) ? (row0 + r) : s_pn[(src >> 1) * 64 + r];
        const __bf16* gp = xbf + (size_t)g * CCH + ch * 8;
        __bf16* lp = smem + (size_t)(it * 256 + w * 64) * 8;   // wave-uniform base
        __builtin_amdgcn_global_load_lds((const __attribute__((address_space(1))) void*)gp,
                                         (__attribute__((address_space(3))) void*)lp,
                                         16, 0, 0);
    }
    __syncthreads();   // DMA drained (vmcnt0 at barrier), A ready

    // ---- MFMA main loop: K=384 in 12 steps, B prefetched 1 ahead ----
    floatx4 acc[2][4];
    #pragma unroll
    for (int mt = 0; mt < 2; ++mt)
        #pragma unroll
        for (int nt = 0; nt < 4; ++nt)
            #pragma unroll
            for (int r = 0; r < 4; ++r) acc[mt][nt][r] = 0.0f;

    const __bf16* wbase = wt + (size_t)a * CCH * KTOT;
    bf16x8 Bc[4], Bn[4];
    #pragma unroll
    for (int nt = 0; nt < 4; ++nt)
        Bc[nt] = *(const bf16x8*)(wbase + (size_t)(wn * 64 + nt * 16 + ln) * KTOT + q * 8);

    #pragma unroll
    for (int ks = 0; ks < 12; ++ks) {
        if (ks < 11) {
            #pragma unroll
            for (int nt = 0; nt < 4; ++nt)
                Bn[nt] = *(const bf16x8*)(wbase + (size_t)(wn * 64 + nt * 16 + ln) * KTOT
                                          + (ks + 1) * 32 + q * 8);
        }
        #pragma unroll
        for (int mt = 0; mt < 2; ++mt) {
            int r = wm * 32 + mt * 16 + ln;
            int chunk = r * 48 + ((ks * 4 + q) ^ (r & 7));
            bf16x8 afr = *(const bf16x8*)(smem + (size_t)chunk * 8);
            #pragma unroll
            for (int nt = 0; nt < 4; ++nt)
                acc[mt][nt] = __builtin_amdgcn_mfma_f32_16x16x32_bf16(afr, Bc[nt], acc[mt][nt], 0, 0, 0);
        }
        #pragma unroll
        for (int nt = 0; nt < 4; ++nt) Bc[nt] = Bn[nt];
    }

    // ---- per-channel sum / sumsq (fp32), quad-reduce then one atomic per (a,col) ----
    #pragma unroll
    for (int nt = 0; nt < 4; ++nt) {
        float s = 0.f, ss = 0.f;
        #pragma unroll
        for (int mt = 0; mt < 2; ++mt)
            #pragma unroll
            for (int r = 0; r < 4; ++r) { float v = acc[mt][nt][r]; s += v; ss += v * v; }
        s  += __shfl_xor(s, 16);  ss += __shfl_xor(ss, 16);
        s  += __shfl_xor(s, 32);  ss += __shfl_xor(ss, 32);
        if (lane < 16) {
            int col = wn * 64 + nt * 16 + lane;
            atomicAdd(&stats[a * 2 * CCH + col], s);
            atomicAdd(&stats[a * 2 * CCH + CCH + col], ss);
        }
    }

    __syncthreads();   // all A-reads done; reuse smem for bf16 out tile (64 x 136)
    // D layout: col = ln (+16nt+64wn), row = q*4 + r (+16mt+32wm)
    #pragma unroll
    for (int mt = 0; mt < 2; ++mt)
        #pragma unroll
        for (int nt = 0; nt < 4; ++nt) {
            int col = wn * 64 + nt * 16 + ln;
            #pragma unroll
            for (int r = 0; r < 4; ++r) {
                int rr = wm * 32 + mt * 16 + q * 4 + r;
                smem[rr * 136 + col] = (__bf16)acc[mt][nt][r];
            }
        }
    __syncthreads();
    #pragma unroll
    for (int it = 0; it < 4; ++it) {
        int i = it * 256 + tid;          // 1024 chunks of 8 bf16
        int r = i >> 4, ch = i & 15;
        bf16x8 v = *(const bf16x8*)(&smem[r * 136 + ch * 8]);
        *(bf16x8*)(outb + ((size_t)a * NVOX + row0 + r) * CCH + ch * 8) = v;
    }
}

// Fold BN stats + gamma/beta into out*scale + shift.
__global__ void k_scales(const float* __restrict__ stats, const float* __restrict__ gamma,
                         const float* __restrict__ beta, float* __restrict__ sc,
                         float* __restrict__ sh) {
    int i = threadIdx.x;
    if (i >= 384) return;
    int a = i >> 7;            // i = a*128 + c
    int c = i & 127;
    float mu  = stats[a * 256 + c] * (1.0f / NVOX);
    float var = stats[a * 256 + 128 + c] * (1.0f / NVOX) - mu * mu;
    float rs  = rsqrtf(var + EPS_BN);
    float g = gamma[i], b = beta[i];
    sc[i] = rs * g;
    sh[i] = b - mu * rs * g;
}

// out[i,c] = features[i,c] * sum_a sigmoid(outb[a,i,c]*sc + sh)
__launch_bounds__(256)
__global__ void k_final(const __bf16* __restrict__ outb, const float* __restrict__ xf,
                        const float* __restrict__ sc, const float* __restrict__ sh,
                        float* __restrict__ out) {
    __shared__ float lsc[384], lsh[384];
    int tid = threadIdx.x;
    for (int i = tid; i < 384; i += 256) { lsc[i] = sc[i]; lsh[i] = sh[i]; }
    __syncthreads();
    const int total = NVOX * 16;
    for (int idx = blockIdx.x * 256 + tid; idx < total; idx += gridDim.x * 256) {
        int c0 = (idx & 15) * 8;
        float4 f0 = ((const float4*)xf)[(size_t)idx * 2];
        float4 f1 = ((const float4*)xf)[(size_t)idx * 2 + 1];
        float r[8];
        #pragma unroll
        for (int j = 0; j < 8; ++j) r[j] = 0.0f;
        #pragma unroll
        for (int a = 0; a < 3; ++a) {
            bf16x8 o = *((const bf16x8*)outb + (size_t)a * NVOX * 16 + idx);
            #pragma unroll
            for (int j = 0; j < 8; ++j) {
                float v = (float)o[j] * lsc[a * 128 + c0 + j] + lsh[a * 128 + c0 + j];
                r[j] += __builtin_amdgcn_rcpf(1.0f + __expf(-v));
            }
        }
        float4 o0, o1;
        o0.x = r[0] * f0.x; o0.y = r[1] * f0.y; o0.z = r[2] * f0.z; o0.w = r[3] * f0.w;
        o1.x = r[4] * f1.x; o1.y = r[5] * f1.y; o1.z = r[6] * f1.z; o1.w = r[7] * f1.w;
        ((float4*)out)[(size_t)idx * 2]     = o0;
        ((float4*)out)[(size_t)idx * 2 + 1] = o1;
    }
}

extern "C" void kernel_launch(void* const* d_in, const int* in_sizes, int n_in,
                              void* d_out, int out_size, void* d_ws, size_t ws_size,
                              hipStream_t stream) {
    const float* xf    = (const float*)d_in[0];
    const int*   nb    = (const int*)  d_in[1];
    const float* W     = (const float*)d_in[2];
    const float* gamma = (const float*)d_in[3];
    const float* beta  = (const float*)d_in[4];
    float* out = (float*)d_out;

    char* ws = (char*)d_ws;
    __bf16* xbf   = (__bf16*)(ws + XBF_OFF);
    __bf16* wt    = (__bf16*)(ws + WT_OFF);
    __bf16* outb  = (__bf16*)(ws + OUTB_OFF);
    float*  stats = (float*)(ws + STATS_OFF);
    float*  sc    = (float*)(ws + SC_OFF);
    float*  sh    = sc + 384;

    hipMemsetAsync(stats, 0, STATS_BYTES, stream);
    k_prep_x<<<((NVOX + 1) * 16 + 255) / 256, 256, 0, stream>>>(xf, xbf);
    k_prep_w<<<(3 * CCH * KTOT + 255) / 256, 256, 0, stream>>>(W, wt);
    k_gemm<<<dim3(NVOX / 64, 3), 256, 0, stream>>>(xbf, wt, nb, outb, stats);
    k_scales<<<1, 384, 0, stream>>>(stats, gamma, beta, sc, sh);
    k_final<<<2048, 256, 0, stream>>>(outb, xf, sc, sh, out);
}

// Round 3
// 415.201 us; speedup vs baseline: 1.4832x; 1.4832x over previous
//
#include <hip/hip_runtime.h>
#include <hip/hip_bf16.h>

#define NVOX 200000
#define CCH  128
#define KTOT 384
#define EPS_BN 1e-5f
#define PB   625          // persistent blocks per axis
#define TPB  5            // tiles per block (625*5 = 3125 = 200000/64)

typedef __bf16 bf16x8 __attribute__((ext_vector_type(8)));
typedef float  floatx4 __attribute__((ext_vector_type(4)));

// ---- workspace layout (bytes) ----
#define XBF_OFF    0ull
#define XBF_BYTES  ((size_t)(NVOX + 1) * CCH * 2)      // bf16 features + zero row
#define WT_OFF     (XBF_OFF + XBF_BYTES)
#define WT_BYTES   ((size_t)3 * CCH * KTOT * 2)        // WT[a][c][k] bf16
#define OUTB_OFF   (WT_OFF + WT_BYTES)
#define OUTB_BYTES ((size_t)3 * NVOX * CCH * 2)        // pre-BN out, bf16
#define STATS_OFF  (OUTB_OFF + OUTB_BYTES)
#define STATS_BYTES ((size_t)3 * 2 * CCH * 4)          // sum/sumsq fp32

// Cast features -> bf16, append one zero row at index NVOX (sentinel gathers read zeros).
__global__ void k_prep_x(const float* __restrict__ xf, __bf16* __restrict__ xbf) {
    int idx = blockIdx.x * blockDim.x + threadIdx.x;   // one 8-channel chunk
    const int total = (NVOX + 1) * 16;
    if (idx >= total) return;
    float v[8];
    if (idx < NVOX * 16) {
        const float4* p = (const float4*)xf + (size_t)idx * 2;
        float4 f0 = p[0], f1 = p[1];
        v[0] = f0.x; v[1] = f0.y; v[2] = f0.z; v[3] = f0.w;
        v[4] = f1.x; v[5] = f1.y; v[6] = f1.z; v[7] = f1.w;
    } else {
        #pragma unroll
        for (int j = 0; j < 8; ++j) v[j] = 0.0f;
    }
    bf16x8 o;
    #pragma unroll
    for (int j = 0; j < 8; ++j) o[j] = (__bf16)v[j];
    *((bf16x8*)xbf + idx) = o;
}

// W[3][3][C][C] (k,c) -> WT[3][C][KTOT] bf16 where k = s*128 + k0 (prev|self|next concat).
__global__ void k_prep_w(const float* __restrict__ W, __bf16* __restrict__ wt) {
    int idx = blockIdx.x * blockDim.x + threadIdx.x;
    if (idx >= 3 * CCH * KTOT) return;
    int k = idx % KTOT; int rem = idx / KTOT;
    int c = rem % CCH;  int a = rem / CCH;
    int s = k >> 7, k0 = k & 127;
    wt[idx] = (__bf16)W[(((size_t)(a * 3 + s) * CCH) + k0) * CCH + c];
}

// Persistent-block GEMM. Block = 4 waves, 1x4 col split (wave w -> cols [32w,32w+32)).
// B for this axis/col-group lives in 96 VGPRs, loaded ONCE (hoisted out of the
// runtime tile loop -> cannot be sunk). Per tile: stage gathered A (64x384,
// stride 392) via registers into LDS, 12-step MFMA K-loop (LDS A x reg B),
// fp32 stats atomics, bf16 out tile via LDS round-trip.
__launch_bounds__(256, 2)
__global__ void k_gemm(const __bf16* __restrict__ xbf, const __bf16* __restrict__ wt,
                       const int* __restrict__ nb, __bf16* __restrict__ outb,
                       float* __restrict__ stats) {
    __shared__ __bf16 smem[64 * 392];   // A tile; tail reused for out staging
    __shared__ int s_pn[128];           // [0..63] prev idx, [64..127] next idx

    const int a    = blockIdx.y;
    const int tid  = threadIdx.x;
    const int w    = tid >> 6;
    const int lane = tid & 63;
    const int q    = lane >> 4;
    const int ln   = lane & 15;

    // ---- B resident in registers for the whole block lifetime ----
    const __bf16* wbase = wt + (size_t)a * CCH * KTOT;
    bf16x8 B0[12], B1[12];
    #pragma unroll
    for (int ks = 0; ks < 12; ++ks) {
        B0[ks] = *(const bf16x8*)(wbase + (size_t)(w * 32 + ln) * KTOT + ks * 32 + q * 8);
        B1[ks] = *(const bf16x8*)(wbase + (size_t)(w * 32 + 16 + ln) * KTOT + ks * 32 + q * 8);
    }

    for (int ti = 0; ti < TPB; ++ti) {
        const int row0 = (blockIdx.x + ti * PB) * 64;

        __syncthreads();   // previous iteration's LDS consumers done
        if (tid < 128)
            s_pn[tid] = nb[(size_t)(a * 2 + (tid >> 6)) * NVOX + row0 + (tid & 63)];
        __syncthreads();

        // ---- stage A tile: 3072 16B chunks; seg 0-15 prev, 16-31 self, 32-47 next ----
        bf16x8 areg[12];
        #pragma unroll
        for (int it = 0; it < 12; ++it) {
            int cc  = it * 256 + tid;
            int r   = cc / 48;
            int seg = cc - r * 48;
            int src = seg >> 4, ch = seg & 15;
            int g = (src == 1) ? (row0 + r) : s_pn[(src >> 1) * 64 + r];
            areg[it] = *(const bf16x8*)(xbf + (size_t)g * CCH + ch * 8);
        }
        #pragma unroll
        for (int it = 0; it < 12; ++it) {
            int cc  = it * 256 + tid;
            int r   = cc / 48;
            int seg = cc - r * 48;
            *(bf16x8*)(&smem[r * 392 + seg * 8]) = areg[it];
        }
        __syncthreads();

        // ---- MFMA K-loop: LDS A frags x register B frags ----
        floatx4 acc0[4], acc1[4];
        #pragma unroll
        for (int mt = 0; mt < 4; ++mt)
            #pragma unroll
            for (int r = 0; r < 4; ++r) { acc0[mt][r] = 0.0f; acc1[mt][r] = 0.0f; }

        #pragma unroll
        for (int ks = 0; ks < 12; ++ks) {
            #pragma unroll
            for (int mt = 0; mt < 4; ++mt) {
                bf16x8 afr = *(const bf16x8*)(&smem[(mt * 16 + ln) * 392 + ks * 32 + q * 8]);
                acc0[mt] = __builtin_amdgcn_mfma_f32_16x16x32_bf16(afr, B0[ks], acc0[mt], 0, 0, 0);
                acc1[mt] = __builtin_amdgcn_mfma_f32_16x16x32_bf16(afr, B1[ks], acc1[mt], 0, 0, 0);
            }
        }

        // ---- per-channel sum / sumsq, quad-reduce then one atomic per (a,col) ----
        {
            float s0 = 0.f, ss0 = 0.f, s1 = 0.f, ss1 = 0.f;
            #pragma unroll
            for (int mt = 0; mt < 4; ++mt)
                #pragma unroll
                for (int r = 0; r < 4; ++r) {
                    float v0 = acc0[mt][r]; s0 += v0; ss0 += v0 * v0;
                    float v1 = acc1[mt][r]; s1 += v1; ss1 += v1 * v1;
                }
            s0 += __shfl_xor(s0, 16); ss0 += __shfl_xor(ss0, 16);
            s0 += __shfl_xor(s0, 32); ss0 += __shfl_xor(ss0, 32);
            s1 += __shfl_xor(s1, 16); ss1 += __shfl_xor(ss1, 16);
            s1 += __shfl_xor(s1, 32); ss1 += __shfl_xor(ss1, 32);
            if (lane < 16) {
                int c0 = w * 32 + lane, c1 = w * 32 + 16 + lane;
                atomicAdd(&stats[a * 2 * CCH + c0], s0);
                atomicAdd(&stats[a * 2 * CCH + CCH + c0], ss0);
                atomicAdd(&stats[a * 2 * CCH + c1], s1);
                atomicAdd(&stats[a * 2 * CCH + CCH + c1], ss1);
            }
        }

        __syncthreads();   // all A-reads done; reuse smem for bf16 out tile (64 x 136)
        // D layout: col = ln (+16nt+32w), row = q*4 + r (+16mt)
        #pragma unroll
        for (int mt = 0; mt < 4; ++mt) {
            #pragma unroll
            for (int r = 0; r < 4; ++r) {
                int rr = mt * 16 + q * 4 + r;
                smem[rr * 136 + w * 32 + ln]      = (__bf16)acc0[mt][r];
                smem[rr * 136 + w * 32 + 16 + ln] = (__bf16)acc1[mt][r];
            }
        }
        __syncthreads();
        #pragma unroll
        for (int it = 0; it < 4; ++it) {
            int i = it * 256 + tid;          // 1024 chunks of 8 bf16
            int r = i >> 4, ch = i & 15;
            bf16x8 v = *(const bf16x8*)(&smem[r * 136 + ch * 8]);
            *(bf16x8*)(outb + ((size_t)a * NVOX + row0 + r) * CCH + ch * 8) = v;
        }
    }
}

// out[i,c] = features[i,c] * sum_a sigmoid(outb[a,i,c]*sc + sh)
// (BN scale/shift computed per block from stats — k_scales fused away)
__launch_bounds__(256)
__global__ void k_final(const __bf16* __restrict__ outb, const float* __restrict__ xf,
                        const float* __restrict__ stats, const float* __restrict__ gamma,
                        const float* __restrict__ beta, float* __restrict__ out) {
    __shared__ float lsc[384], lsh[384];
    int tid = threadIdx.x;
    for (int i = tid; i < 384; i += 256) {
        int a = i >> 7, c = i & 127;
        float mu  = stats[a * 256 + c] * (1.0f / NVOX);
        float var = stats[a * 256 + 128 + c] * (1.0f / NVOX) - mu * mu;
        float rs  = rsqrtf(var + EPS_BN);
        float g = gamma[i], b = beta[i];
        lsc[i] = rs * g;
        lsh[i] = b - mu * rs * g;
    }
    __syncthreads();
    const int total = NVOX * 16;
    for (int idx = blockIdx.x * 256 + tid; idx < total; idx += gridDim.x * 256) {
        int c0 = (idx & 15) * 8;
        float4 f0 = ((const float4*)xf)[(size_t)idx * 2];
        float4 f1 = ((const float4*)xf)[(size_t)idx * 2 + 1];
        float r[8];
        #pragma unroll
        for (int j = 0; j < 8; ++j) r[j] = 0.0f;
        #pragma unroll
        for (int a = 0; a < 3; ++a) {
            bf16x8 o = *((const bf16x8*)outb + (size_t)a * NVOX * 16 + idx);
            #pragma unroll
            for (int j = 0; j < 8; ++j) {
                float v = (float)o[j] * lsc[a * 128 + c0 + j] + lsh[a * 128 + c0 + j];
                r[j] += __builtin_amdgcn_rcpf(1.0f + __expf(-v));
            }
        }
        float4 o0, o1;
        o0.x = r[0] * f0.x; o0.y = r[1] * f0.y; o0.z = r[2] * f0.z; o0.w = r[3] * f0.w;
        o1.x = r[4] * f1.x; o1.y = r[5] * f1.y; o1.z = r[6] * f1.z; o1.w = r[7] * f1.w;
        ((float4*)out)[(size_t)idx * 2]     = o0;
        ((float4*)out)[(size_t)idx * 2 + 1] = o1;
    }
}

extern "C" void kernel_launch(void* const* d_in, const int* in_sizes, int n_in,
                              void* d_out, int out_size, void* d_ws, size_t ws_size,
                              hipStream_t stream) {
    const float* xf    = (const float*)d_in[0];
    const int*   nb    = (const int*)  d_in[1];
    const float* W     = (const float*)d_in[2];
    const float* gamma = (const float*)d_in[3];
    const float* beta  = (const float*)d_in[4];
    float* out = (float*)d_out;

    char* ws = (char*)d_ws;
    __bf16* xbf   = (__bf16*)(ws + XBF_OFF);
    __bf16* wt    = (__bf16*)(ws + WT_OFF);
    __bf16* outb  = (__bf16*)(ws + OUTB_OFF);
    float*  stats = (float*)(ws + STATS_OFF);

    hipMemsetAsync(stats, 0, STATS_BYTES, stream);
    k_prep_x<<<((NVOX + 1) * 16 + 255) / 256, 256, 0, stream>>>(xf, xbf);
    k_prep_w<<<(3 * CCH * KTOT + 255) / 256, 256, 0, stream>>>(W, wt);
    k_gemm<<<dim3(PB, 3), 256, 0, stream>>>(xbf, wt, nb, outb, stats);
    k_final<<<2048, 256, 0, stream>>>(outb, xf, stats, gamma, beta, out);
}